// Round 7
// baseline (4233.995 us; speedup 1.0000x reference)
//
#include <hip/hip_runtime.h>
#include <stdint.h>

namespace {

constexpr int B_ROWS = 131072;

typedef __attribute__((ext_vector_type(8))) short bf16x8;
typedef __attribute__((ext_vector_type(4))) float f32x4;

__device__ __forceinline__ unsigned short f2bf(float f) {
  unsigned u = __builtin_bit_cast(unsigned, f);
  u += 0x7fffu + ((u >> 16) & 1u);
  return (unsigned short)(u >> 16);
}
__device__ __forceinline__ float bf2f(unsigned short h) {
  unsigned u = ((unsigned)h) << 16;
  return __builtin_bit_cast(float, u);
}
__device__ __forceinline__ float sigm(float v) { return 1.0f / (1.0f + __expf(-v)); }

// ---------- weight packing ----------

__global__ void pack_t_k(const float* __restrict__ W, unsigned short* __restrict__ Wt) {
  int idx = blockIdx.x * 256 + threadIdx.x;  // 512*512
  int n = idx >> 9, k = idx & 511;
  Wt[idx] = f2bf(W[(k << 9) + n]);
}

__global__ void pack_zgr_k(const float* __restrict__ dgmW, unsigned short* __restrict__ Wt) {
  long idx = (long)blockIdx.x * 256 + threadIdx.x;  // 3*1536*1024
  int l = (int)(idx / (1536 * 1024));
  int rest = (int)(idx - (long)l * (1536 * 1024));
  int n = rest >> 10, k = rest & 1023;
  int g = n >> 9, nn = n & 511;
  const int xi0[3] = {0, 3, 6};
  const int xi1[3] = {2, 4, 8};
  const int si[3] = {1, 5, 7};
  float v;
  if (k < 512)
    v = dgmW[(((long)(l * 12 + xi0[g]) << 9) + k) * 512 + nn] +
        dgmW[(((long)(l * 12 + xi1[g]) << 9) + k) * 512 + nn];
  else
    v = dgmW[(((long)(l * 12 + si[g]) << 9) + (k - 512)) * 512 + nn];
  Wt[idx] = f2bf(v);
}

__global__ void pack_h_k(const float* __restrict__ dgmW, unsigned short* __restrict__ Wt) {
  long idx = (long)blockIdx.x * 256 + threadIdx.x;  // 3*512*1024
  int l = (int)(idx / (512 * 1024));
  int rest = (int)(idx - (long)l * (512 * 1024));
  int n = rest >> 10, k = rest & 1023;
  float v;
  if (k < 512)
    v = dgmW[(((long)(l * 12 + 9) << 9) + k) * 512 + n] +
        dgmW[(((long)(l * 12 + 11) << 9) + k) * 512 + n];
  else
    v = dgmW[(((long)(l * 12 + 10) << 9) + (k - 512)) * 512 + n];
  Wt[idx] = f2bf(v);
}

__global__ void pack_bias_k(const float* __restrict__ dgmb, float* __restrict__ bzgr,
                            float* __restrict__ bh) {
  int idx = blockIdx.x * 256 + threadIdx.x;  // 3*2048
  if (idx >= 3 * 2048) return;
  int l = idx >> 11, n = idx & 2047;
  const float* bl = dgmb + l * 12 * 512;
  if (n < 1536) {
    int g = n >> 9, nn = n & 511;
    bzgr[l * 1536 + n] =
        bl[(g * 3 + 0) * 512 + nn] + bl[(g * 3 + 1) * 512 + nn] + bl[(g * 3 + 2) * 512 + nn];
  } else {
    int nn = n - 1536;
    bh[l * 512 + nn] = bl[9 * 512 + nn] + bl[10 * 512 + nn] + bl[11 * 512 + nn];
  }
}

// ---------- front input layer ----------
__global__ void front0_k(const float* __restrict__ X, const float* __restrict__ t,
                         const float* __restrict__ Win, const float* __restrict__ bin,
                         unsigned short* __restrict__ x0, long row0) {
  long idx = (long)blockIdx.x * 256 + threadIdx.x;  // rows*512
  long r = idx >> 9;
  int c = (int)(idx & 511);
  long gr = row0 + r;
  float a = X[gr * 2] * Win[c] + X[gr * 2 + 1] * Win[512 + c] + t[gr] * Win[1024 + c] + bin[c];
  x0[idx] = f2bf(tanhf(a));
}

// ---------- output head ----------
__global__ void head_k(const unsigned short* __restrict__ S, const float* __restrict__ Wout,
                       const float* __restrict__ bout, float* __restrict__ out, long row0) {
  const int lane = threadIdx.x & 63, wid = threadIdx.x >> 6;
  const long r = (long)blockIdx.x * 4 + wid;
  bf16x8 sv = *(const bf16x8*)&S[r * 512 + lane * 8];
  float sum = 0.f;
#pragma unroll
  for (int i = 0; i < 8; ++i) sum += bf2f((unsigned short)sv[i]) * Wout[lane * 8 + i];
#pragma unroll
  for (int off = 32; off > 0; off >>= 1) sum += __shfl_down(sum, off);
  if (lane == 0) out[row0 + r] = sum + bout[0];
}

// ---------- persistent-M 256x256 8-phase GEMM (R6, unchanged: the anchor) ----------
template <int EPI, int KT, int LOGKT, int NCOL>
__global__ __launch_bounds__(512, 2) void gemmP_k(
    const unsigned short* __restrict__ a0, const unsigned short* __restrict__ a1,
    const unsigned short* __restrict__ wt, const float* __restrict__ bias,
    unsigned short* __restrict__ o0, unsigned short* __restrict__ o1,
    unsigned short* __restrict__ o2, const unsigned short* __restrict__ e0,
    const unsigned short* __restrict__ e1, int njobs, int jpb) {
  constexpr int K = KT * 64;
  extern __shared__ unsigned short lds[];
  const int tid = threadIdx.x;
  const int lane = tid & 63, wid = tid >> 6;
  const int wm = wid >> 2, wn = wid & 3;
  const int lr = lane & 15, kk = lane >> 4;

  const int G = gridDim.x;
  const int q = G >> 3, rr = G & 7;
  const int xcd = (int)blockIdx.x & 7, lo = (int)blockIdx.x >> 3;
  const int bsw = ((xcd < rr) ? xcd * (q + 1) : rr * (q + 1) + (xcd - rr) * q) + lo;
  const int j0 = bsw * jpb;
  if (j0 >= njobs) return;
  const int nj = min(jpb, njobs - j0);
  const int nseq = nj << LOGKT;

  const int gp8 = ((kk ^ ((lr >> 1) & 3)) << 3);
  const int a_rd = (wm * 128 + lr) * 32 + gp8;
  const int b_rd = 16384 + (wn * 64 + lr) * 32 + gp8;
  const int r0 = tid >> 2, gl0 = (tid & 3) ^ ((r0 >> 1) & 3);
  const int c1 = tid + 512, r1 = c1 >> 2, gl1 = (c1 & 3) ^ ((r1 >> 1) & 3);
  const int aL0 = r0 * 512 + gl0 * 8, aL1 = r1 * 512 + gl1 * 8;
  const size_t bL0 = (size_t)r0 * K + gl0 * 8, bL1 = (size_t)r1 * K + gl1 * 8;
  const int dL0 = tid * 8, dL1 = (tid + 512) * 8;

  f32x4 acc[8][4] = {};
  bf16x8 afA[4], afB[4], bfA[4], bfB[4];

  auto stA = [&](int s2, int ks) {
    if (s2 >= nseq) return;
    const int jj = j0 + (s2 >> LOGKT);
    const int mt = jj / NCOL;
    const int kt2 = s2 & (KT - 1);
    const unsigned short* src = (KT == 16 && (kt2 & 8)) ? a1 : a0;
    const long pb = (long)mt * 131072 + (kt2 & 7) * 64 + ks * 32;
    const int d = ((s2 & 1) << 15) + ks * 8192;
    __builtin_amdgcn_global_load_lds(
        (const __attribute__((address_space(1))) void*)(src + pb + aL0),
        (__attribute__((address_space(3))) void*)(lds + d + dL0), 16, 0, 0);
    __builtin_amdgcn_global_load_lds(
        (const __attribute__((address_space(1))) void*)(src + pb + aL1),
        (__attribute__((address_space(3))) void*)(lds + d + dL1), 16, 0, 0);
  };
  auto stB = [&](int s2, int ks) {
    if (s2 >= nseq) return;
    const int jj = j0 + (s2 >> LOGKT);
    const int col = jj % NCOL;
    const int kt2 = s2 & (KT - 1);
    const size_t pb = (size_t)col * (256 * K) + kt2 * 64 + ks * 32;
    const int d = ((s2 & 1) << 15) + 16384 + ks * 8192;
    __builtin_amdgcn_global_load_lds(
        (const __attribute__((address_space(1))) void*)(wt + pb + bL0),
        (__attribute__((address_space(3))) void*)(lds + d + dL0), 16, 0, 0);
    __builtin_amdgcn_global_load_lds(
        (const __attribute__((address_space(1))) void*)(wt + pb + bL1),
        (__attribute__((address_space(3))) void*)(lds + d + dL1), 16, 0, 0);
  };

#define LDA(dst, cbo_, mh, ks_)                                                           \
  _Pragma("unroll") for (int _m = 0; _m < 4; ++_m) dst[_m] =                              \
      *(const bf16x8*)(lds + (cbo_) + (ks_)*8192 + a_rd + (mh)*2048 + _m * 512);

#define LDB(dst, cbo_, ks_)                                                               \
  _Pragma("unroll") for (int _n = 0; _n < 4; ++_n) dst[_n] =                              \
      *(const bf16x8*)(lds + (cbo_) + (ks_)*8192 + b_rd + _n * 512);

#define MMQ(mh, AF, BF)                                                                   \
  do {                                                                                    \
    __builtin_amdgcn_s_setprio(1);                                                        \
    _Pragma("unroll") for (int _m = 0; _m < 4; ++_m) _Pragma("unroll") for (int _n = 0;   \
                                                                            _n < 4; ++_n) \
        acc[(mh)*4 + _m][_n] = __builtin_amdgcn_mfma_f32_16x16x32_bf16(                   \
            AF[_m], BF[_n], acc[(mh)*4 + _m][_n], 0, 0, 0);                               \
    __builtin_amdgcn_s_setprio(0);                                                        \
  } while (0)

  stB(0, 0);
  stA(0, 0);
  stB(0, 1);
  stA(0, 1);
  stB(1, 0);
  stA(1, 0);
  stB(1, 1);
  asm volatile("s_waitcnt vmcnt(10)" ::: "memory");
  __builtin_amdgcn_s_barrier();
  LDB(bfA, 0, 0);
  LDA(afA, 0, 0, 0);

  for (int s = 0; s < nseq; ++s) {
    const int cbo = (s & 1) << 15;
    const int cbn = cbo ^ 32768;
    const bool deep = (s + 4 <= nseq);
    LDA(afB, cbo, 1, 0);
    stA(s + 1, 1);
    __builtin_amdgcn_s_barrier();
    MMQ(0, afA, bfA);
    __builtin_amdgcn_s_barrier();
    if (deep)
      asm volatile("s_waitcnt vmcnt(8)" ::: "memory");
    else
      asm volatile("s_waitcnt vmcnt(0)" ::: "memory");
    LDB(bfB, cbo, 1);
    LDA(afA, cbo, 0, 1);
    stB(s + 2, 0);
    __builtin_amdgcn_s_barrier();
    MMQ(1, afB, bfA);
    __builtin_amdgcn_s_barrier();
    LDA(afB, cbo, 1, 1);
    stA(s + 2, 0);
    __builtin_amdgcn_s_barrier();
    MMQ(0, afA, bfB);
    __builtin_amdgcn_s_barrier();
    if (deep)
      asm volatile("s_waitcnt vmcnt(8)" ::: "memory");
    else
      asm volatile("s_waitcnt vmcnt(0)" ::: "memory");
    LDB(bfA, cbn, 0);
    LDA(afA, cbn, 0, 0);
    stB(s + 2, 1);
    __builtin_amdgcn_s_barrier();
    MMQ(1, afB, bfB);
    __builtin_amdgcn_s_barrier();

    if ((s & (KT - 1)) == (KT - 1)) {
      const int jj = j0 + (s >> LOGKT);
      const long brow = (long)(jj / NCOL) * 256;
      const int bcol = (jj % NCOL) * 256;
#pragma unroll
      for (int m = 0; m < 8; ++m) {
#pragma unroll
        for (int n = 0; n < 4; ++n) {
          const int col = bcol + wn * 64 + n * 16 + lr;
          const float bs = bias[col];
#pragma unroll
          for (int j = 0; j < 4; ++j) {
            const long row = brow + wm * 128 + m * 16 + kk * 4 + j;
            float v = acc[m][n][j] + bs;
            if constexpr (EPI == 0) {
              o0[row * 512 + col] = f2bf(tanhf(v));
            } else if constexpr (EPI == 1) {
              unsigned short b = f2bf(v);
              o0[row * 512 + col] = b;
              o1[row * 512 + col] = b;
            } else if constexpr (EPI == 2) {
              const int g = col >> 9;
              const int nn = col & 511;
              const float sgv = sigm(v);
              if (g == 0) {
                o0[row * 512 + nn] = f2bf(sgv * bf2f(e0[row * 512 + nn]));  // Z*S
              } else if (g == 1) {
                o1[row * 512 + nn] = f2bf(1.0f - sgv);  // 1-G
              } else {
                o2[row * 512 + nn] = f2bf(sgv * bf2f(e0[row * 512 + nn]));  // S*R
              }
            } else {
              const float h = tanhf(v);
              const float omg = bf2f(e0[row * 512 + col]);
              const float zs = bf2f(e1[row * 512 + col]);
              o0[row * 512 + col] = f2bf(omg * h + zs);  // S_new
            }
            acc[m][n][j] = 0.0f;
          }
        }
      }
    }
  }
#undef LDA
#undef LDB
#undef MMQ
}

// ---------- ABLATION PROBES (diagnostic; write only to ws scratch) ----------
// Clone of the gate gemmP_k<2,16,4,6> inner machinery with one subsystem
// removed. ABL: 1=NOSTAGE (no global_load_lds / no vmcnt), 2=NOREAD (no
// in-loop ds_reads), 3=NOMFMA (XOR keep-alive instead), 4=NOBAR (no
// barriers / no waits: free-running pipe superposition). Runs 2x the gate
// job count (wrap jj mod njreal) so probes rank above real gates in top-5.
template <int ABL>
__device__ __forceinline__ void probe_body(unsigned short* lds, const unsigned short* a0,
                                           const unsigned short* a1,
                                           const unsigned short* wt, const float* bias,
                                           unsigned short* scr, int scrmask, int njobs2,
                                           int njreal, int jpb) {
  constexpr int KT = 16, LOGKT = 4, NCOL = 6, K = 1024;
  const int tid = threadIdx.x;
  const int lane = tid & 63, wid = tid >> 6;
  const int wm = wid >> 2, wn = wid & 3;
  const int lr = lane & 15, kk = lane >> 4;

  const int G = gridDim.x;
  const int q = G >> 3, rr = G & 7;
  const int xcd = (int)blockIdx.x & 7, lo = (int)blockIdx.x >> 3;
  const int bsw = ((xcd < rr) ? xcd * (q + 1) : rr * (q + 1) + (xcd - rr) * q) + lo;
  const int j0 = bsw * jpb;
  if (j0 >= njobs2) return;
  const int nj = min(jpb, njobs2 - j0);
  const int nseq = nj << LOGKT;

  const int gp8 = ((kk ^ ((lr >> 1) & 3)) << 3);
  const int a_rd = (wm * 128 + lr) * 32 + gp8;
  const int b_rd = 16384 + (wn * 64 + lr) * 32 + gp8;
  const int r0 = tid >> 2, gl0 = (tid & 3) ^ ((r0 >> 1) & 3);
  const int c1 = tid + 512, r1 = c1 >> 2, gl1 = (c1 & 3) ^ ((r1 >> 1) & 3);
  const int aL0 = r0 * 512 + gl0 * 8, aL1 = r1 * 512 + gl1 * 8;
  const size_t bL0 = (size_t)r0 * K + gl0 * 8, bL1 = (size_t)r1 * K + gl1 * 8;
  const int dL0 = tid * 8, dL1 = (tid + 512) * 8;

  f32x4 acc[8][4] = {};
  bf16x8 afA[4], afB[4], bfA[4], bfB[4];
  int iacc = 0;

  auto jmap = [&](int s2) {
    int jj = j0 + (s2 >> LOGKT);
    if (jj >= njreal) jj -= njreal;
    return jj;
  };
  auto stA = [&](int s2, int ks) {
    if constexpr (ABL == 1) return;
    if (s2 >= nseq) return;
    const int jj = jmap(s2);
    const int mt = jj / NCOL;
    const int kt2 = s2 & (KT - 1);
    const unsigned short* src = (kt2 & 8) ? a1 : a0;
    const long pb = (long)mt * 131072 + (kt2 & 7) * 64 + ks * 32;
    const int d = ((s2 & 1) << 15) + ks * 8192;
    __builtin_amdgcn_global_load_lds(
        (const __attribute__((address_space(1))) void*)(src + pb + aL0),
        (__attribute__((address_space(3))) void*)(lds + d + dL0), 16, 0, 0);
    __builtin_amdgcn_global_load_lds(
        (const __attribute__((address_space(1))) void*)(src + pb + aL1),
        (__attribute__((address_space(3))) void*)(lds + d + dL1), 16, 0, 0);
  };
  auto stB = [&](int s2, int ks) {
    if constexpr (ABL == 1) return;
    if (s2 >= nseq) return;
    const int jj = jmap(s2);
    const int col = jj % NCOL;
    const int kt2 = s2 & (KT - 1);
    const size_t pb = (size_t)col * (256 * K) + kt2 * 64 + ks * 32;
    const int d = ((s2 & 1) << 15) + 16384 + ks * 8192;
    __builtin_amdgcn_global_load_lds(
        (const __attribute__((address_space(1))) void*)(wt + pb + bL0),
        (__attribute__((address_space(3))) void*)(lds + d + dL0), 16, 0, 0);
    __builtin_amdgcn_global_load_lds(
        (const __attribute__((address_space(1))) void*)(wt + pb + bL1),
        (__attribute__((address_space(3))) void*)(lds + d + dL1), 16, 0, 0);
  };

#define PLDA(dst, cbo_, mh, ks_)                                                          \
  _Pragma("unroll") for (int _m = 0; _m < 4; ++_m) dst[_m] =                              \
      *(const bf16x8*)(lds + (cbo_) + (ks_)*8192 + a_rd + (mh)*2048 + _m * 512);

#define PLDB(dst, cbo_, ks_)                                                              \
  _Pragma("unroll") for (int _n = 0; _n < 4; ++_n) dst[_n] =                              \
      *(const bf16x8*)(lds + (cbo_) + (ks_)*8192 + b_rd + _n * 512);

#define PMMQ(mh, AF, BF)                                                                  \
  do {                                                                                    \
    if constexpr (ABL == 3) {                                                             \
      iacc ^= ((const int*)&AF[0])[0] ^ ((const int*)&BF[0])[0];                          \
    } else {                                                                              \
      __builtin_amdgcn_s_setprio(1);                                                      \
      _Pragma("unroll") for (int _m = 0; _m < 4; ++_m)                                    \
          _Pragma("unroll") for (int _n = 0; _n < 4; ++_n) acc[(mh)*4 + _m][_n] =         \
              __builtin_amdgcn_mfma_f32_16x16x32_bf16(AF[_m], BF[_n],                     \
                                                      acc[(mh)*4 + _m][_n], 0, 0, 0);     \
      __builtin_amdgcn_s_setprio(0);                                                      \
    }                                                                                     \
  } while (0)

#define PBAR()                                     \
  do {                                             \
    if constexpr (ABL != 4) __builtin_amdgcn_s_barrier(); \
  } while (0)

  stB(0, 0);
  stA(0, 0);
  stB(0, 1);
  stA(0, 1);
  stB(1, 0);
  stA(1, 0);
  stB(1, 1);
  if constexpr (ABL != 1 && ABL != 4) asm volatile("s_waitcnt vmcnt(10)" ::: "memory");
  PBAR();
  PLDB(bfA, 0, 0);
  PLDA(afA, 0, 0, 0);
  PLDB(bfB, 0, 1);
  PLDA(afB, 0, 1, 0);

  for (int s = 0; s < nseq; ++s) {
    const int cbo = (s & 1) << 15;
    const int cbn = cbo ^ 32768;
    const bool deep = (s + 4 <= nseq);
    if constexpr (ABL != 2) PLDA(afB, cbo, 1, 0);
    stA(s + 1, 1);
    PBAR();
    PMMQ(0, afA, bfA);
    PBAR();
    if constexpr (ABL != 1 && ABL != 4) {
      if (deep)
        asm volatile("s_waitcnt vmcnt(8)" ::: "memory");
      else
        asm volatile("s_waitcnt vmcnt(0)" ::: "memory");
    }
    if constexpr (ABL != 2) {
      PLDB(bfB, cbo, 1);
      PLDA(afA, cbo, 0, 1);
    }
    stB(s + 2, 0);
    PBAR();
    PMMQ(1, afB, bfA);
    PBAR();
    if constexpr (ABL != 2) PLDA(afB, cbo, 1, 1);
    stA(s + 2, 0);
    PBAR();
    PMMQ(0, afA, bfB);
    PBAR();
    if constexpr (ABL != 1 && ABL != 4) {
      if (deep)
        asm volatile("s_waitcnt vmcnt(8)" ::: "memory");
      else
        asm volatile("s_waitcnt vmcnt(0)" ::: "memory");
    }
    if constexpr (ABL != 2) {
      PLDB(bfA, cbn, 0);
      PLDA(afA, cbn, 0, 0);
    }
    stB(s + 2, 1);
    PBAR();
    PMMQ(1, afB, bfB);
    PBAR();

    if ((s & (KT - 1)) == (KT - 1)) {
      const int jj = jmap(s);
      const long brow = (long)(jj / NCOL) * 256;
      const int bcol = (jj % NCOL) * 256;
#pragma unroll
      for (int m = 0; m < 8; ++m) {
#pragma unroll
        for (int n = 0; n < 4; ++n) {
          const int col = bcol + wn * 64 + n * 16 + lr;
          const float bs = bias[col];
#pragma unroll
          for (int j = 0; j < 4; ++j) {
            const long row = brow + wm * 128 + m * 16 + kk * 4 + j;
            float v = acc[m][n][j] + bs;
            const int nn = col & 511;
            scr[(int)((row * 512 + nn)) & scrmask] = f2bf(sigm(v));
            acc[m][n][j] = 0.0f;
          }
        }
      }
    }
  }
  if constexpr (ABL == 3) scr[(unsigned)(j0 * 512 + tid) & scrmask] = (unsigned short)iacc;
#undef PLDA
#undef PLDB
#undef PMMQ
#undef PBAR
}

__global__ __launch_bounds__(512, 2) void probe_nostage_k(
    const unsigned short* a0, const unsigned short* a1, const unsigned short* wt,
    const float* bias, unsigned short* scr, int scrmask, int njobs2, int njreal, int jpb) {
  extern __shared__ unsigned short l[];
  probe_body<1>(l, a0, a1, wt, bias, scr, scrmask, njobs2, njreal, jpb);
}
__global__ __launch_bounds__(512, 2) void probe_noread_k(
    const unsigned short* a0, const unsigned short* a1, const unsigned short* wt,
    const float* bias, unsigned short* scr, int scrmask, int njobs2, int njreal, int jpb) {
  extern __shared__ unsigned short l[];
  probe_body<2>(l, a0, a1, wt, bias, scr, scrmask, njobs2, njreal, jpb);
}
__global__ __launch_bounds__(512, 2) void probe_nomfma_k(
    const unsigned short* a0, const unsigned short* a1, const unsigned short* wt,
    const float* bias, unsigned short* scr, int scrmask, int njobs2, int njreal, int jpb) {
  extern __shared__ unsigned short l[];
  probe_body<3>(l, a0, a1, wt, bias, scr, scrmask, njobs2, njreal, jpb);
}
__global__ __launch_bounds__(512, 2) void probe_nobar_k(
    const unsigned short* a0, const unsigned short* a1, const unsigned short* wt,
    const float* bias, unsigned short* scr, int scrmask, int njobs2, int njreal, int jpb) {
  extern __shared__ unsigned short l[];
  probe_body<4>(l, a0, a1, wt, bias, scr, scrmask, njobs2, njreal, jpb);
}

}  // namespace

extern "C" void kernel_launch(void* const* d_in, const int* in_sizes, int n_in,
                              void* d_out, int out_size, void* d_ws, size_t ws_size,
                              hipStream_t stream) {
  const float* X = (const float*)d_in[0];
  const float* t = (const float*)d_in[1];
  const float* W_in = (const float*)d_in[2];
  const float* b_in = (const float*)d_in[3];
  const float* W_h1 = (const float*)d_in[4];
  const float* b_h1 = (const float*)d_in[5];
  const float* W_hd = (const float*)d_in[6];
  const float* b_hd = (const float*)d_in[7];
  const float* dgm_W = (const float*)d_in[8];
  const float* dgm_b = (const float*)d_in[9];
  const float* W_out = (const float*)d_in[10];
  const float* b_out = (const float*)d_in[11];
  float* out = (float*)d_out;
  char* ws = (char*)d_ws;

  (void)hipFuncSetAttribute((const void*)&gemmP_k<0, 8, 3, 2>,
                            hipFuncAttributeMaxDynamicSharedMemorySize, 131072);
  (void)hipFuncSetAttribute((const void*)&gemmP_k<1, 8, 3, 2>,
                            hipFuncAttributeMaxDynamicSharedMemorySize, 131072);
  (void)hipFuncSetAttribute((const void*)&gemmP_k<2, 16, 4, 6>,
                            hipFuncAttributeMaxDynamicSharedMemorySize, 131072);
  (void)hipFuncSetAttribute((const void*)&gemmP_k<3, 16, 4, 2>,
                            hipFuncAttributeMaxDynamicSharedMemorySize, 131072);
  (void)hipFuncSetAttribute((const void*)&probe_nostage_k,
                            hipFuncAttributeMaxDynamicSharedMemorySize, 131072);
  (void)hipFuncSetAttribute((const void*)&probe_noread_k,
                            hipFuncAttributeMaxDynamicSharedMemorySize, 131072);
  (void)hipFuncSetAttribute((const void*)&probe_nomfma_k,
                            hipFuncAttributeMaxDynamicSharedMemorySize, 131072);
  (void)hipFuncSetAttribute((const void*)&probe_nobar_k,
                            hipFuncAttributeMaxDynamicSharedMemorySize, 131072);

  size_t off = 0;
  auto alloc = [&](size_t bytes) {
    size_t o = off;
    off = (off + bytes + 255) & ~(size_t)255;
    return o;
  };
  size_t o_wth1 = alloc((size_t)512 * 512 * 2);
  size_t o_wthd = alloc((size_t)512 * 512 * 2);
  size_t o_wtzgr = alloc((size_t)3 * 1536 * 1024 * 2);
  size_t o_wth = alloc((size_t)3 * 512 * 1024 * 2);
  size_t o_bzgr = alloc((size_t)3 * 1536 * 4);
  size_t o_bh = alloc((size_t)3 * 512 * 4);
  size_t actoff = off;

  unsigned short* wth1 = (unsigned short*)(ws + o_wth1);
  unsigned short* wthd = (unsigned short*)(ws + o_wthd);
  unsigned short* wtzgr = (unsigned short*)(ws + o_wtzgr);
  unsigned short* wth = (unsigned short*)(ws + o_wth);
  float* bzgr = (float*)(ws + o_bzgr);
  float* bh = (float*)(ws + o_bh);

  size_t avail = ws_size > actoff ? ws_size - actoff : 0;
  int nch = 1;
  while (nch < 256 && (size_t)(B_ROWS / nch) * 512 * 2 * 5 > avail) nch <<= 1;
  const int R = B_ROWS / nch;
  unsigned short* xb = (unsigned short*)(ws + actoff);
  unsigned short* Sb = xb + (size_t)R * 512;
  unsigned short* ZSb = Sb + (size_t)R * 512;
  unsigned short* OGb = ZSb + (size_t)R * 512;
  unsigned short* SRb = OGb + (size_t)R * 512;

  pack_t_k<<<1024, 256, 0, stream>>>(W_h1, wth1);
  pack_t_k<<<1024, 256, 0, stream>>>(W_hd, wthd);
  pack_zgr_k<<<18432, 256, 0, stream>>>(dgm_W, wtzgr);
  pack_h_k<<<6144, 256, 0, stream>>>(dgm_W, wth);
  pack_bias_k<<<24, 256, 0, stream>>>(dgm_b, bzgr, bh);

  const int MT = R / 256;
  auto cfg = [](int njobs, int& jpb, int& G) {
    jpb = (njobs + 255) / 256;
    G = (njobs + jpb - 1) / jpb;
  };
  int nj2 = 2 * MT, jpb2, G2;
  cfg(nj2, jpb2, G2);
  int nj6 = 6 * MT, jpb6, G6;
  cfg(nj6, jpb6, G6);

  for (int c = 0; c < nch; ++c) {
    long row0 = (long)c * R;
    front0_k<<<R * 2, 256, 0, stream>>>(X, t, W_in, b_in, ZSb, row0);
    gemmP_k<0, 8, 3, 2><<<G2, 512, 131072, stream>>>(ZSb, ZSb, wth1, b_h1, OGb, nullptr,
                                                     nullptr, nullptr, nullptr, nj2, jpb2);
    gemmP_k<1, 8, 3, 2><<<G2, 512, 131072, stream>>>(OGb, OGb, wthd, b_hd, xb, Sb, nullptr,
                                                     nullptr, nullptr, nj2, jpb2);
    for (int l = 0; l < 3; ++l) {
      gemmP_k<2, 16, 4, 6><<<G6, 512, 131072, stream>>>(
          xb, Sb, wtzgr + (size_t)l * 1536 * 1024, bzgr + l * 1536, ZSb, OGb, SRb, Sb,
          nullptr, nj6, jpb6);
      gemmP_k<3, 16, 4, 2><<<G2, 512, 131072, stream>>>(
          xb, SRb, wth + (size_t)l * 512 * 1024, bh + l * 512, Sb, nullptr, nullptr, OGb,
          ZSb, nj2, jpb2);
    }
    head_k<<<R / 4, 256, 0, stream>>>(Sb, W_out, b_out, out, row0);
  }

  // ---- diagnostic probes (2x gate workload each; scratch = ZSb, fully
  // recomputed by front0_k before any read on subsequent calls) ----
  {
    int nj2x = 2 * nj6, jpb2x = 2 * jpb6;
    int scrmask = R * 512 - 1;
    probe_nobar_k<<<G6, 512, 131072, stream>>>(xb, Sb, wtzgr, bzgr, ZSb, scrmask, nj2x,
                                               nj6, jpb2x);
    probe_nostage_k<<<G6, 512, 131072, stream>>>(xb, Sb, wtzgr, bzgr, ZSb, scrmask, nj2x,
                                                 nj6, jpb2x);
    probe_noread_k<<<G6, 512, 131072, stream>>>(xb, Sb, wtzgr, bzgr, ZSb, scrmask, nj2x,
                                                nj6, jpb2x);
    probe_nomfma_k<<<G6, 512, 131072, stream>>>(xb, Sb, wtzgr, bzgr, ZSb, scrmask, nj2x,
                                                nj6, jpb2x);
  }
}

// Round 8
// 3423.803 us; speedup vs baseline: 1.2366x; 1.2366x over previous
//
#include <hip/hip_runtime.h>
#include <stdint.h>

namespace {

constexpr int B_ROWS = 131072;

typedef __attribute__((ext_vector_type(8))) short bf16x8;
typedef __attribute__((ext_vector_type(4))) float f32x4;

__device__ __forceinline__ unsigned short f2bf(float f) {
  unsigned u = __builtin_bit_cast(unsigned, f);
  u += 0x7fffu + ((u >> 16) & 1u);
  return (unsigned short)(u >> 16);
}
__device__ __forceinline__ float bf2f(unsigned short h) {
  unsigned u = ((unsigned)h) << 16;
  return __builtin_bit_cast(float, u);
}
__device__ __forceinline__ float sigm(float v) { return 1.0f / (1.0f + __expf(-v)); }

// raw hardware barrier WITHOUT the compiler's implicit vmcnt(0)/lgkmcnt(0)
// drain (R7 ablation: nobar recovered >=38%; theory = builtin s_barrier gets
// __syncthreads-style waitcnt insertion). "memory" clobber still orders
// memory ops at compile time; explicit counted vmcnt + data-dep lgkm carry
// the hardware-side correctness (cross-wave via barrier transitivity).
__device__ __forceinline__ void bar_asm() { asm volatile("s_barrier" ::: "memory"); }

// ---------- weight packing ----------

__global__ void pack_t_k(const float* __restrict__ W, unsigned short* __restrict__ Wt) {
  int idx = blockIdx.x * 256 + threadIdx.x;  // 512*512
  int n = idx >> 9, k = idx & 511;
  Wt[idx] = f2bf(W[(k << 9) + n]);
}

__global__ void pack_zgr_k(const float* __restrict__ dgmW, unsigned short* __restrict__ Wt) {
  long idx = (long)blockIdx.x * 256 + threadIdx.x;  // 3*1536*1024
  int l = (int)(idx / (1536 * 1024));
  int rest = (int)(idx - (long)l * (1536 * 1024));
  int n = rest >> 10, k = rest & 1023;
  int g = n >> 9, nn = n & 511;
  const int xi0[3] = {0, 3, 6};
  const int xi1[3] = {2, 4, 8};
  const int si[3] = {1, 5, 7};
  float v;
  if (k < 512)
    v = dgmW[(((long)(l * 12 + xi0[g]) << 9) + k) * 512 + nn] +
        dgmW[(((long)(l * 12 + xi1[g]) << 9) + k) * 512 + nn];
  else
    v = dgmW[(((long)(l * 12 + si[g]) << 9) + (k - 512)) * 512 + nn];
  Wt[idx] = f2bf(v);
}

__global__ void pack_h_k(const float* __restrict__ dgmW, unsigned short* __restrict__ Wt) {
  long idx = (long)blockIdx.x * 256 + threadIdx.x;  // 3*512*1024
  int l = (int)(idx / (512 * 1024));
  int rest = (int)(idx - (long)l * (512 * 1024));
  int n = rest >> 10, k = rest & 1023;
  float v;
  if (k < 512)
    v = dgmW[(((long)(l * 12 + 9) << 9) + k) * 512 + n] +
        dgmW[(((long)(l * 12 + 11) << 9) + k) * 512 + n];
  else
    v = dgmW[(((long)(l * 12 + 10) << 9) + (k - 512)) * 512 + n];
  Wt[idx] = f2bf(v);
}

__global__ void pack_bias_k(const float* __restrict__ dgmb, float* __restrict__ bzgr,
                            float* __restrict__ bh) {
  int idx = blockIdx.x * 256 + threadIdx.x;  // 3*2048
  if (idx >= 3 * 2048) return;
  int l = idx >> 11, n = idx & 2047;
  const float* bl = dgmb + l * 12 * 512;
  if (n < 1536) {
    int g = n >> 9, nn = n & 511;
    bzgr[l * 1536 + n] =
        bl[(g * 3 + 0) * 512 + nn] + bl[(g * 3 + 1) * 512 + nn] + bl[(g * 3 + 2) * 512 + nn];
  } else {
    int nn = n - 1536;
    bh[l * 512 + nn] = bl[9 * 512 + nn] + bl[10 * 512 + nn] + bl[11 * 512 + nn];
  }
}

// ---------- front input layer ----------
__global__ void front0_k(const float* __restrict__ X, const float* __restrict__ t,
                         const float* __restrict__ Win, const float* __restrict__ bin,
                         unsigned short* __restrict__ x0, long row0) {
  long idx = (long)blockIdx.x * 256 + threadIdx.x;  // rows*512
  long r = idx >> 9;
  int c = (int)(idx & 511);
  long gr = row0 + r;
  float a = X[gr * 2] * Win[c] + X[gr * 2 + 1] * Win[512 + c] + t[gr] * Win[1024 + c] + bin[c];
  x0[idx] = f2bf(tanhf(a));
}

// ---------- output head ----------
__global__ void head_k(const unsigned short* __restrict__ S, const float* __restrict__ Wout,
                       const float* __restrict__ bout, float* __restrict__ out, long row0) {
  const int lane = threadIdx.x & 63, wid = threadIdx.x >> 6;
  const long r = (long)blockIdx.x * 4 + wid;
  bf16x8 sv = *(const bf16x8*)&S[r * 512 + lane * 8];
  float sum = 0.f;
#pragma unroll
  for (int i = 0; i < 8; ++i) sum += bf2f((unsigned short)sv[i]) * Wout[lane * 8 + i];
#pragma unroll
  for (int off = 32; off > 0; off >>= 1) sum += __shfl_down(sum, off);
  if (lane == 0) out[row0 + r] = sum + bout[0];
}

// ---------- persistent-M 256x256 8-phase GEMM (R6 structure, asm barriers) ----------
template <int EPI, int KT, int LOGKT, int NCOL>
__global__ __launch_bounds__(512, 2) void gemmP_k(
    const unsigned short* __restrict__ a0, const unsigned short* __restrict__ a1,
    const unsigned short* __restrict__ wt, const float* __restrict__ bias,
    unsigned short* __restrict__ o0, unsigned short* __restrict__ o1,
    unsigned short* __restrict__ o2, const unsigned short* __restrict__ e0,
    const unsigned short* __restrict__ e1, int njobs, int jpb) {
  constexpr int K = KT * 64;
  extern __shared__ unsigned short lds[];
  const int tid = threadIdx.x;
  const int lane = tid & 63, wid = tid >> 6;
  const int wm = wid >> 2, wn = wid & 3;
  const int lr = lane & 15, kk = lane >> 4;

  const int G = gridDim.x;
  const int q = G >> 3, rr = G & 7;
  const int xcd = (int)blockIdx.x & 7, lo = (int)blockIdx.x >> 3;
  const int bsw = ((xcd < rr) ? xcd * (q + 1) : rr * (q + 1) + (xcd - rr) * q) + lo;
  const int j0 = bsw * jpb;
  if (j0 >= njobs) return;
  const int nj = min(jpb, njobs - j0);
  const int nseq = nj << LOGKT;

  const int gp8 = ((kk ^ ((lr >> 1) & 3)) << 3);
  const int a_rd = (wm * 128 + lr) * 32 + gp8;
  const int b_rd = 16384 + (wn * 64 + lr) * 32 + gp8;
  const int r0 = tid >> 2, gl0 = (tid & 3) ^ ((r0 >> 1) & 3);
  const int c1 = tid + 512, r1 = c1 >> 2, gl1 = (c1 & 3) ^ ((r1 >> 1) & 3);
  const int aL0 = r0 * 512 + gl0 * 8, aL1 = r1 * 512 + gl1 * 8;
  const size_t bL0 = (size_t)r0 * K + gl0 * 8, bL1 = (size_t)r1 * K + gl1 * 8;
  const int dL0 = tid * 8, dL1 = (tid + 512) * 8;

  f32x4 acc[8][4] = {};
  bf16x8 afA[4], afB[4], bfA[4], bfB[4];

  auto stA = [&](int s2, int ks) {
    if (s2 >= nseq) return;
    const int jj = j0 + (s2 >> LOGKT);
    const int mt = jj / NCOL;
    const int kt2 = s2 & (KT - 1);
    const unsigned short* src = (KT == 16 && (kt2 & 8)) ? a1 : a0;
    const long pb = (long)mt * 131072 + (kt2 & 7) * 64 + ks * 32;
    const int d = ((s2 & 1) << 15) + ks * 8192;
    __builtin_amdgcn_global_load_lds(
        (const __attribute__((address_space(1))) void*)(src + pb + aL0),
        (__attribute__((address_space(3))) void*)(lds + d + dL0), 16, 0, 0);
    __builtin_amdgcn_global_load_lds(
        (const __attribute__((address_space(1))) void*)(src + pb + aL1),
        (__attribute__((address_space(3))) void*)(lds + d + dL1), 16, 0, 0);
  };
  auto stB = [&](int s2, int ks) {
    if (s2 >= nseq) return;
    const int jj = j0 + (s2 >> LOGKT);
    const int col = jj % NCOL;
    const int kt2 = s2 & (KT - 1);
    const size_t pb = (size_t)col * (256 * K) + kt2 * 64 + ks * 32;
    const int d = ((s2 & 1) << 15) + 16384 + ks * 8192;
    __builtin_amdgcn_global_load_lds(
        (const __attribute__((address_space(1))) void*)(wt + pb + bL0),
        (__attribute__((address_space(3))) void*)(lds + d + dL0), 16, 0, 0);
    __builtin_amdgcn_global_load_lds(
        (const __attribute__((address_space(1))) void*)(wt + pb + bL1),
        (__attribute__((address_space(3))) void*)(lds + d + dL1), 16, 0, 0);
  };

#define LDA(dst, cbo_, mh, ks_)                                                           \
  _Pragma("unroll") for (int _m = 0; _m < 4; ++_m) dst[_m] =                              \
      *(const bf16x8*)(lds + (cbo_) + (ks_)*8192 + a_rd + (mh)*2048 + _m * 512);

#define LDB(dst, cbo_, ks_)                                                               \
  _Pragma("unroll") for (int _n = 0; _n < 4; ++_n) dst[_n] =                              \
      *(const bf16x8*)(lds + (cbo_) + (ks_)*8192 + b_rd + _n * 512);

#define MMQ(mh, AF, BF)                                                                   \
  do {                                                                                    \
    __builtin_amdgcn_s_setprio(1);                                                        \
    _Pragma("unroll") for (int _m = 0; _m < 4; ++_m) _Pragma("unroll") for (int _n = 0;   \
                                                                            _n < 4; ++_n) \
        acc[(mh)*4 + _m][_n] = __builtin_amdgcn_mfma_f32_16x16x32_bf16(                   \
            AF[_m], BF[_n], acc[(mh)*4 + _m][_n], 0, 0, 0);                               \
    __builtin_amdgcn_s_setprio(0);                                                        \
  } while (0)

  stB(0, 0);
  stA(0, 0);
  stB(0, 1);
  stA(0, 1);
  stB(1, 0);
  stA(1, 0);
  stB(1, 1);
  asm volatile("s_waitcnt vmcnt(10)" ::: "memory");
  bar_asm();
  LDB(bfA, 0, 0);
  LDA(afA, 0, 0, 0);

  for (int s = 0; s < nseq; ++s) {
    const int cbo = (s & 1) << 15;
    const int cbn = cbo ^ 32768;
    const bool deep = (s + 4 <= nseq);
    // P1: MFMA rows0-3 (ks0); read afB = A(m4-7,ks0); stage A(s+1,ks1)
    LDA(afB, cbo, 1, 0);
    stA(s + 1, 1);
    bar_asm();
    MMQ(0, afA, bfA);
    bar_asm();
    // P2: vmcnt gates tile-s ks1 region; read ks1 frags; stage B(s+2,ks0)
    if (deep)
      asm volatile("s_waitcnt vmcnt(8)" ::: "memory");
    else
      asm volatile("s_waitcnt vmcnt(0)" ::: "memory");
    LDB(bfB, cbo, 1);
    LDA(afA, cbo, 0, 1);
    stB(s + 2, 0);
    bar_asm();
    MMQ(1, afB, bfA);
    bar_asm();
    // P3: read afB = A(m4-7,ks1); stage A(s+2,ks0)
    LDA(afB, cbo, 1, 1);
    stA(s + 2, 0);
    bar_asm();
    MMQ(0, afA, bfB);
    bar_asm();
    // P4: vmcnt gates tile-(s+1) ks0 region; read next-tile ks0; stage B(s+2,ks1)
    if (deep)
      asm volatile("s_waitcnt vmcnt(8)" ::: "memory");
    else
      asm volatile("s_waitcnt vmcnt(0)" ::: "memory");
    LDB(bfA, cbn, 0);
    LDA(afA, cbn, 0, 0);
    stB(s + 2, 1);
    bar_asm();
    MMQ(1, afB, bfB);
    bar_asm();

    if ((s & (KT - 1)) == (KT - 1)) {
      const int jj = j0 + (s >> LOGKT);
      const long brow = (long)(jj / NCOL) * 256;
      const int bcol = (jj % NCOL) * 256;
#pragma unroll
      for (int m = 0; m < 8; ++m) {
#pragma unroll
        for (int n = 0; n < 4; ++n) {
          const int col = bcol + wn * 64 + n * 16 + lr;
          const float bs = bias[col];
#pragma unroll
          for (int j = 0; j < 4; ++j) {
            const long row = brow + wm * 128 + m * 16 + kk * 4 + j;
            float v = acc[m][n][j] + bs;
            if constexpr (EPI == 0) {
              o0[row * 512 + col] = f2bf(tanhf(v));
            } else if constexpr (EPI == 1) {
              unsigned short b = f2bf(v);
              o0[row * 512 + col] = b;
              o1[row * 512 + col] = b;
            } else if constexpr (EPI == 2) {
              const int g = col >> 9;
              const int nn = col & 511;
              const float sgv = sigm(v);
              if (g == 0) {
                o0[row * 512 + nn] = f2bf(sgv * bf2f(e0[row * 512 + nn]));  // Z*S
              } else if (g == 1) {
                o1[row * 512 + nn] = f2bf(1.0f - sgv);  // 1-G
              } else {
                o2[row * 512 + nn] = f2bf(sgv * bf2f(e0[row * 512 + nn]));  // S*R
              }
            } else {
              const float h = tanhf(v);
              const float omg = bf2f(e0[row * 512 + col]);
              const float zs = bf2f(e1[row * 512 + col]);
              o0[row * 512 + col] = f2bf(omg * h + zs);  // S_new
            }
            acc[m][n][j] = 0.0f;
          }
        }
      }
    }
  }
#undef LDA
#undef LDB
#undef MMQ
}

}  // namespace

extern "C" void kernel_launch(void* const* d_in, const int* in_sizes, int n_in,
                              void* d_out, int out_size, void* d_ws, size_t ws_size,
                              hipStream_t stream) {
  const float* X = (const float*)d_in[0];
  const float* t = (const float*)d_in[1];
  const float* W_in = (const float*)d_in[2];
  const float* b_in = (const float*)d_in[3];
  const float* W_h1 = (const float*)d_in[4];
  const float* b_h1 = (const float*)d_in[5];
  const float* W_hd = (const float*)d_in[6];
  const float* b_hd = (const float*)d_in[7];
  const float* dgm_W = (const float*)d_in[8];
  const float* dgm_b = (const float*)d_in[9];
  const float* W_out = (const float*)d_in[10];
  const float* b_out = (const float*)d_in[11];
  float* out = (float*)d_out;
  char* ws = (char*)d_ws;

  (void)hipFuncSetAttribute((const void*)&gemmP_k<0, 8, 3, 2>,
                            hipFuncAttributeMaxDynamicSharedMemorySize, 131072);
  (void)hipFuncSetAttribute((const void*)&gemmP_k<1, 8, 3, 2>,
                            hipFuncAttributeMaxDynamicSharedMemorySize, 131072);
  (void)hipFuncSetAttribute((const void*)&gemmP_k<2, 16, 4, 6>,
                            hipFuncAttributeMaxDynamicSharedMemorySize, 131072);
  (void)hipFuncSetAttribute((const void*)&gemmP_k<3, 16, 4, 2>,
                            hipFuncAttributeMaxDynamicSharedMemorySize, 131072);

  size_t off = 0;
  auto alloc = [&](size_t bytes) {
    size_t o = off;
    off = (off + bytes + 255) & ~(size_t)255;
    return o;
  };
  size_t o_wth1 = alloc((size_t)512 * 512 * 2);
  size_t o_wthd = alloc((size_t)512 * 512 * 2);
  size_t o_wtzgr = alloc((size_t)3 * 1536 * 1024 * 2);
  size_t o_wth = alloc((size_t)3 * 512 * 1024 * 2);
  size_t o_bzgr = alloc((size_t)3 * 1536 * 4);
  size_t o_bh = alloc((size_t)3 * 512 * 4);
  size_t actoff = off;

  unsigned short* wth1 = (unsigned short*)(ws + o_wth1);
  unsigned short* wthd = (unsigned short*)(ws + o_wthd);
  unsigned short* wtzgr = (unsigned short*)(ws + o_wtzgr);
  unsigned short* wth = (unsigned short*)(ws + o_wth);
  float* bzgr = (float*)(ws + o_bzgr);
  float* bh = (float*)(ws + o_bh);

  size_t avail = ws_size > actoff ? ws_size - actoff : 0;
  int nch = 1;
  while (nch < 256 && (size_t)(B_ROWS / nch) * 512 * 2 * 5 > avail) nch <<= 1;
  const int R = B_ROWS / nch;
  unsigned short* xb = (unsigned short*)(ws + actoff);
  unsigned short* Sb = xb + (size_t)R * 512;
  unsigned short* ZSb = Sb + (size_t)R * 512;
  unsigned short* OGb = ZSb + (size_t)R * 512;
  unsigned short* SRb = OGb + (size_t)R * 512;

  pack_t_k<<<1024, 256, 0, stream>>>(W_h1, wth1);
  pack_t_k<<<1024, 256, 0, stream>>>(W_hd, wthd);
  pack_zgr_k<<<18432, 256, 0, stream>>>(dgm_W, wtzgr);
  pack_h_k<<<6144, 256, 0, stream>>>(dgm_W, wth);
  pack_bias_k<<<24, 256, 0, stream>>>(dgm_b, bzgr, bh);

  const int MT = R / 256;
  auto cfg = [](int njobs, int& jpb, int& G) {
    jpb = (njobs + 255) / 256;
    G = (njobs + jpb - 1) / jpb;
  };
  int nj2 = 2 * MT, jpb2, G2;
  cfg(nj2, jpb2, G2);
  int nj6 = 6 * MT, jpb6, G6;
  cfg(nj6, jpb6, G6);

  for (int c = 0; c < nch; ++c) {
    long row0 = (long)c * R;
    front0_k<<<R * 2, 256, 0, stream>>>(X, t, W_in, b_in, ZSb, row0);
    gemmP_k<0, 8, 3, 2><<<G2, 512, 131072, stream>>>(ZSb, ZSb, wth1, b_h1, OGb, nullptr,
                                                     nullptr, nullptr, nullptr, nj2, jpb2);
    gemmP_k<1, 8, 3, 2><<<G2, 512, 131072, stream>>>(OGb, OGb, wthd, b_hd, xb, Sb, nullptr,
                                                     nullptr, nullptr, nj2, jpb2);
    for (int l = 0; l < 3; ++l) {
      gemmP_k<2, 16, 4, 6><<<G6, 512, 131072, stream>>>(
          xb, Sb, wtzgr + (size_t)l * 1536 * 1024, bzgr + l * 1536, ZSb, OGb, SRb, Sb,
          nullptr, nj6, jpb6);
      gemmP_k<3, 16, 4, 2><<<G2, 512, 131072, stream>>>(
          xb, SRb, wth + (size_t)l * 512 * 1024, bh + l * 512, Sb, nullptr, nullptr, OGb,
          ZSb, nj2, jpb2);
    }
    head_k<<<R / 4, 256, 0, stream>>>(Sb, W_out, b_out, out, row0);
  }
}

// Round 9
// 3385.211 us; speedup vs baseline: 1.2507x; 1.0114x over previous
//
#include <hip/hip_runtime.h>
#include <stdint.h>

namespace {

constexpr int B_ROWS = 131072;

typedef __attribute__((ext_vector_type(8))) short bf16x8;
typedef __attribute__((ext_vector_type(4))) float f32x4;

__device__ __forceinline__ unsigned short f2bf(float f) {
  unsigned u = __builtin_bit_cast(unsigned, f);
  u += 0x7fffu + ((u >> 16) & 1u);
  return (unsigned short)(u >> 16);
}
__device__ __forceinline__ float bf2f(unsigned short h) {
  unsigned u = ((unsigned)h) << 16;
  return __builtin_bit_cast(float, u);
}
__device__ __forceinline__ float sigm(float v) { return 1.0f / (1.0f + __expf(-v)); }

// ---------- weight packing ----------

__global__ void pack_t_k(const float* __restrict__ W, unsigned short* __restrict__ Wt) {
  int idx = blockIdx.x * 256 + threadIdx.x;  // 512*512
  int n = idx >> 9, k = idx & 511;
  Wt[idx] = f2bf(W[(k << 9) + n]);
}

__global__ void pack_zgr_k(const float* __restrict__ dgmW, unsigned short* __restrict__ Wt) {
  long idx = (long)blockIdx.x * 256 + threadIdx.x;  // 3*1536*1024
  int l = (int)(idx / (1536 * 1024));
  int rest = (int)(idx - (long)l * (1536 * 1024));
  int n = rest >> 10, k = rest & 1023;
  int g = n >> 9, nn = n & 511;
  const int xi0[3] = {0, 3, 6};
  const int xi1[3] = {2, 4, 8};
  const int si[3] = {1, 5, 7};
  float v;
  if (k < 512)
    v = dgmW[(((long)(l * 12 + xi0[g]) << 9) + k) * 512 + nn] +
        dgmW[(((long)(l * 12 + xi1[g]) << 9) + k) * 512 + nn];
  else
    v = dgmW[(((long)(l * 12 + si[g]) << 9) + (k - 512)) * 512 + nn];
  Wt[idx] = f2bf(v);
}

__global__ void pack_h_k(const float* __restrict__ dgmW, unsigned short* __restrict__ Wt) {
  long idx = (long)blockIdx.x * 256 + threadIdx.x;  // 3*512*1024
  int l = (int)(idx / (512 * 1024));
  int rest = (int)(idx - (long)l * (512 * 1024));
  int n = rest >> 10, k = rest & 1023;
  float v;
  if (k < 512)
    v = dgmW[(((long)(l * 12 + 9) << 9) + k) * 512 + n] +
        dgmW[(((long)(l * 12 + 11) << 9) + k) * 512 + n];
  else
    v = dgmW[(((long)(l * 12 + 10) << 9) + (k - 512)) * 512 + n];
  Wt[idx] = f2bf(v);
}

__global__ void pack_bias_k(const float* __restrict__ dgmb, float* __restrict__ bzgr,
                            float* __restrict__ bh) {
  int idx = blockIdx.x * 256 + threadIdx.x;  // 3*2048
  if (idx >= 3 * 2048) return;
  int l = idx >> 11, n = idx & 2047;
  const float* bl = dgmb + l * 12 * 512;
  if (n < 1536) {
    int g = n >> 9, nn = n & 511;
    bzgr[l * 1536 + n] =
        bl[(g * 3 + 0) * 512 + nn] + bl[(g * 3 + 1) * 512 + nn] + bl[(g * 3 + 2) * 512 + nn];
  } else {
    int nn = n - 1536;
    bh[l * 512 + nn] = bl[9 * 512 + nn] + bl[10 * 512 + nn] + bl[11 * 512 + nn];
  }
}

// ---------- front input layer ----------
__global__ void front0_k(const float* __restrict__ X, const float* __restrict__ t,
                         const float* __restrict__ Win, const float* __restrict__ bin,
                         unsigned short* __restrict__ x0, long row0) {
  long idx = (long)blockIdx.x * 256 + threadIdx.x;  // rows*512
  long r = idx >> 9;
  int c = (int)(idx & 511);
  long gr = row0 + r;
  float a = X[gr * 2] * Win[c] + X[gr * 2 + 1] * Win[512 + c] + t[gr] * Win[1024 + c] + bin[c];
  x0[idx] = f2bf(tanhf(a));
}

// ---------- output head ----------
__global__ void head_k(const unsigned short* __restrict__ S, const float* __restrict__ Wout,
                       const float* __restrict__ bout, float* __restrict__ out, long row0) {
  const int lane = threadIdx.x & 63, wid = threadIdx.x >> 6;
  const long r = (long)blockIdx.x * 4 + wid;
  bf16x8 sv = *(const bf16x8*)&S[r * 512 + lane * 8];
  float sum = 0.f;
#pragma unroll
  for (int i = 0; i < 8; ++i) sum += bf2f((unsigned short)sv[i]) * Wout[lane * 8 + i];
#pragma unroll
  for (int off = 32; off > 0; off >>= 1) sum += __shfl_down(sum, off);
  if (lane == 0) out[row0 + r] = sum + bout[0];
}

#define GLD(gsrc, ldst)                                                      \
  __builtin_amdgcn_global_load_lds(                                          \
      (const __attribute__((address_space(1))) void*)(gsrc),                 \
      (__attribute__((address_space(3))) void*)(ldst), 16, 0, 0)

// ---------- 2-phase double-buffered 256x256 GEMM (catalog T3 minimal) ----------
// Per K-tile: stage(t+1 -> other buf) ; read ks0 frags ; 32 MFMA ;
// read ks1 frags ; 32 MFMA ; vmcnt(0) ; __syncthreads(). ONE barrier/tile,
// all reads in two bursts, all MFMAs in two clusters (m230-V0=682 TF,
// m248 2ph=655 @K=1024 -- the verified references for this regime).
// LDS [2 buf][A: 2 ks x 256 x 32 | B: same] = 128 KiB. Swizzle: granule
// ^= (row>>1)&3 on global source and ds_read (LDS dest linear); measured
// 0 bank conflicts in R2-R8.
template <int EPI, int KT>
__global__ __launch_bounds__(512, 2) void gemm2_k(
    const unsigned short* __restrict__ a0, const unsigned short* __restrict__ a1,
    const unsigned short* __restrict__ wt, const float* __restrict__ bias,
    unsigned short* __restrict__ o0, unsigned short* __restrict__ o1,
    unsigned short* __restrict__ o2, const unsigned short* __restrict__ e0,
    const unsigned short* __restrict__ e1) {
  constexpr int K = KT * 64;
  extern __shared__ unsigned short lds[];
  const int tid = threadIdx.x;
  const int lane = tid & 63, wid = tid >> 6;
  const int wm = wid >> 2, wn = wid & 3;
  const int lr = lane & 15, kk = lane >> 4;

  // bijective XCD swizzle (m204), col-fastest (R2 config: lowest FETCH)
  const int gx = gridDim.x;
  const int nwg = gx * (int)gridDim.y;
  const int orig = (int)blockIdx.y * gx + (int)blockIdx.x;
  const int q = nwg >> 3, rr = nwg & 7;
  const int xcd = orig & 7, lo = orig >> 3;
  const int wg = ((xcd < rr) ? xcd * (q + 1) : rr * (q + 1) + (xcd - rr) * q) + lo;
  const long brow = (long)(wg / gx) * 256;
  const int bcol = (wg % gx) * 256;

  // lane-constant LDS read bases (swizzle granule = kk ^ ((lr>>1)&3))
  const int gp8 = ((kk ^ ((lr >> 1) & 3)) << 3);
  const int a_rd = (wm * 128 + lr) * 32 + gp8;         // + m*512 + ks*8192 + buf
  const int b_rd = 16384 + (wn * 64 + lr) * 32 + gp8;  // + n*512 + ks*8192 + buf
  // stage lane pieces (inverse swizzle on global source, linear LDS dest)
  const int r0 = tid >> 2, gl0 = (tid & 3) ^ ((r0 >> 1) & 3);
  const int c1t = tid + 512, r1 = c1t >> 2, gl1 = (c1t & 3) ^ ((r1 >> 1) & 3);
  const int aL0 = r0 * 512 + gl0 * 8, aL1 = r1 * 512 + gl1 * 8;
  const size_t bL0 = (size_t)r0 * K + gl0 * 8, bL1 = (size_t)r1 * K + gl1 * 8;
  const int dL0 = tid * 8, dL1 = (tid + 512) * 8;

  f32x4 acc[8][4] = {};
  bf16x8 af[8], bf[4];

  const long abase = brow * 512;
  const size_t bbase = (size_t)bcol * K;

  auto stA = [&](int kt, int ks, int dbo) {
    const unsigned short* src = (KT == 16 && (kt & 8)) ? a1 : a0;
    const long pb = abase + (kt & 7) * 64 + ks * 32;
    const int d = dbo + ks * 8192;
    GLD(src + pb + aL0, lds + d + dL0);
    GLD(src + pb + aL1, lds + d + dL1);
  };
  auto stB = [&](int kt, int ks, int dbo) {
    const size_t pb = bbase + kt * 64 + ks * 32;
    const int d = dbo + 16384 + ks * 8192;
    GLD(wt + pb + bL0, lds + d + dL0);
    GLD(wt + pb + bL1, lds + d + dL1);
  };

  // prologue: full tile 0 into buf0
  stA(0, 0, 0);
  stB(0, 0, 0);
  stA(0, 1, 0);
  stB(0, 1, 0);
  asm volatile("s_waitcnt vmcnt(0)" ::: "memory");
  __syncthreads();

  for (int t = 0; t < KT; ++t) {
    const int cbo = (t & 1) << 15;
    const int nbo = cbo ^ 32768;
    // stage next tile first: its HBM latency spans this tile's compute
    if (t + 1 < KT) {
      stA(t + 1, 0, nbo);
      stB(t + 1, 0, nbo);
      stA(t + 1, 1, nbo);
      stB(t + 1, 1, nbo);
    }
#pragma unroll
    for (int ks = 0; ks < 2; ++ks) {
      const int ko = cbo + ks * 8192;
#pragma unroll
      for (int n = 0; n < 4; ++n) bf[n] = *(const bf16x8*)(lds + ko + b_rd + n * 512);
#pragma unroll
      for (int m = 0; m < 8; ++m) af[m] = *(const bf16x8*)(lds + ko + a_rd + m * 512);
      __builtin_amdgcn_s_setprio(1);
#pragma unroll
      for (int m = 0; m < 8; ++m)
#pragma unroll
        for (int n = 0; n < 4; ++n)
          acc[m][n] = __builtin_amdgcn_mfma_f32_16x16x32_bf16(af[m], bf[n], acc[m][n], 0, 0, 0);
      __builtin_amdgcn_s_setprio(0);
    }
    asm volatile("s_waitcnt vmcnt(0)" ::: "memory");
    __syncthreads();
  }

  // epilogue
#pragma unroll
  for (int m = 0; m < 8; ++m) {
#pragma unroll
    for (int n = 0; n < 4; ++n) {
      const int col = bcol + wn * 64 + n * 16 + lr;
      const float bs = bias[col];
#pragma unroll
      for (int j = 0; j < 4; ++j) {
        const long row = brow + wm * 128 + m * 16 + kk * 4 + j;
        float v = acc[m][n][j] + bs;
        if constexpr (EPI == 0) {
          o0[row * 512 + col] = f2bf(tanhf(v));
        } else if constexpr (EPI == 1) {
          unsigned short b = f2bf(v);
          o0[row * 512 + col] = b;
          o1[row * 512 + col] = b;
        } else if constexpr (EPI == 2) {
          const int g = col >> 9;
          const int nn = col & 511;
          const float sgv = sigm(v);
          if (g == 0) {
            o0[row * 512 + nn] = f2bf(sgv * bf2f(e0[row * 512 + nn]));  // Z*S
          } else if (g == 1) {
            o1[row * 512 + nn] = f2bf(1.0f - sgv);  // 1-G
          } else {
            o2[row * 512 + nn] = f2bf(sgv * bf2f(e0[row * 512 + nn]));  // S*R
          }
        } else {
          const float h = tanhf(v);
          const float omg = bf2f(e0[row * 512 + col]);
          const float zs = bf2f(e1[row * 512 + col]);
          o0[row * 512 + col] = f2bf(omg * h + zs);  // S_new
        }
      }
    }
  }
}

}  // namespace

extern "C" void kernel_launch(void* const* d_in, const int* in_sizes, int n_in,
                              void* d_out, int out_size, void* d_ws, size_t ws_size,
                              hipStream_t stream) {
  const float* X = (const float*)d_in[0];
  const float* t = (const float*)d_in[1];
  const float* W_in = (const float*)d_in[2];
  const float* b_in = (const float*)d_in[3];
  const float* W_h1 = (const float*)d_in[4];
  const float* b_h1 = (const float*)d_in[5];
  const float* W_hd = (const float*)d_in[6];
  const float* b_hd = (const float*)d_in[7];
  const float* dgm_W = (const float*)d_in[8];
  const float* dgm_b = (const float*)d_in[9];
  const float* W_out = (const float*)d_in[10];
  const float* b_out = (const float*)d_in[11];
  float* out = (float*)d_out;
  char* ws = (char*)d_ws;

  (void)hipFuncSetAttribute((const void*)&gemm2_k<0, 8>,
                            hipFuncAttributeMaxDynamicSharedMemorySize, 131072);
  (void)hipFuncSetAttribute((const void*)&gemm2_k<1, 8>,
                            hipFuncAttributeMaxDynamicSharedMemorySize, 131072);
  (void)hipFuncSetAttribute((const void*)&gemm2_k<2, 16>,
                            hipFuncAttributeMaxDynamicSharedMemorySize, 131072);
  (void)hipFuncSetAttribute((const void*)&gemm2_k<3, 16>,
                            hipFuncAttributeMaxDynamicSharedMemorySize, 131072);

  size_t off = 0;
  auto alloc = [&](size_t bytes) {
    size_t o = off;
    off = (off + bytes + 255) & ~(size_t)255;
    return o;
  };
  size_t o_wth1 = alloc((size_t)512 * 512 * 2);
  size_t o_wthd = alloc((size_t)512 * 512 * 2);
  size_t o_wtzgr = alloc((size_t)3 * 1536 * 1024 * 2);
  size_t o_wth = alloc((size_t)3 * 512 * 1024 * 2);
  size_t o_bzgr = alloc((size_t)3 * 1536 * 4);
  size_t o_bh = alloc((size_t)3 * 512 * 4);
  size_t actoff = off;

  unsigned short* wth1 = (unsigned short*)(ws + o_wth1);
  unsigned short* wthd = (unsigned short*)(ws + o_wthd);
  unsigned short* wtzgr = (unsigned short*)(ws + o_wtzgr);
  unsigned short* wth = (unsigned short*)(ws + o_wth);
  float* bzgr = (float*)(ws + o_bzgr);
  float* bh = (float*)(ws + o_bh);

  size_t avail = ws_size > actoff ? ws_size - actoff : 0;
  int nch = 1;
  while (nch < 256 && (size_t)(B_ROWS / nch) * 512 * 2 * 5 > avail) nch <<= 1;
  const int R = B_ROWS / nch;
  unsigned short* xb = (unsigned short*)(ws + actoff);
  unsigned short* Sb = xb + (size_t)R * 512;
  unsigned short* ZSb = Sb + (size_t)R * 512;
  unsigned short* OGb = ZSb + (size_t)R * 512;
  unsigned short* SRb = OGb + (size_t)R * 512;

  pack_t_k<<<1024, 256, 0, stream>>>(W_h1, wth1);
  pack_t_k<<<1024, 256, 0, stream>>>(W_hd, wthd);
  pack_zgr_k<<<18432, 256, 0, stream>>>(dgm_W, wtzgr);
  pack_h_k<<<6144, 256, 0, stream>>>(dgm_W, wth);
  pack_bias_k<<<24, 256, 0, stream>>>(dgm_b, bzgr, bh);

  const int MT = R / 256;
  for (int c = 0; c < nch; ++c) {
    long row0 = (long)c * R;
    dim3 g2(2, MT), g6(6, MT);
    // x0 = tanh(inp@W_in + b_in)  -> ZSb (scratch)
    front0_k<<<R * 2, 256, 0, stream>>>(X, t, W_in, b_in, ZSb, row0);
    // x1 = tanh(x0@W_h1 + b_h1)   -> OGb (scratch)
    gemm2_k<0, 8><<<g2, 512, 131072, stream>>>(ZSb, ZSb, wth1, b_h1, OGb, nullptr, nullptr,
                                               nullptr, nullptr);
    // x = x1@W_hd + b_hd          -> xb and Sb
    gemm2_k<1, 8><<<g2, 512, 131072, stream>>>(OGb, OGb, wthd, b_hd, xb, Sb, nullptr,
                                               nullptr, nullptr);
    for (int l = 0; l < 3; ++l) {
      // gates: [x|S] @ Wzgr -> Z*S, 1-G, S*R
      gemm2_k<2, 16><<<g6, 512, 131072, stream>>>(xb, Sb, wtzgr + (size_t)l * 1536 * 1024,
                                                  bzgr + l * 1536, ZSb, OGb, SRb, Sb, nullptr);
      // H + S update: [x|S*R] @ Wh ; S = (1-G)*tanh + Z*S
      gemm2_k<3, 16><<<g2, 512, 131072, stream>>>(xb, SRb, wth + (size_t)l * 512 * 1024,
                                                  bh + l * 512, Sb, nullptr, nullptr, OGb, ZSb);
    }
    head_k<<<R / 4, 256, 0, stream>>>(Sb, W_out, b_out, out, row0);
  }
}

// Round 10
// 3012.644 us; speedup vs baseline: 1.4054x; 1.1237x over previous
//
#include <hip/hip_runtime.h>
#include <stdint.h>

namespace {

constexpr int B_ROWS = 131072;

typedef __attribute__((ext_vector_type(8))) short bf16x8;
typedef __attribute__((ext_vector_type(4))) float f32x4;

__device__ __forceinline__ unsigned short f2bf(float f) {
  unsigned u = __builtin_bit_cast(unsigned, f);
  u += 0x7fffu + ((u >> 16) & 1u);
  return (unsigned short)(u >> 16);
}
__device__ __forceinline__ float bf2f(unsigned short h) {
  unsigned u = ((unsigned)h) << 16;
  return __builtin_bit_cast(float, u);
}
__device__ __forceinline__ float sigm(float v) { return 1.0f / (1.0f + __expf(-v)); }

// ---------- weight packing ----------

__global__ void pack_t_k(const float* __restrict__ W, unsigned short* __restrict__ Wt) {
  int idx = blockIdx.x * 256 + threadIdx.x;  // 512*512
  int n = idx >> 9, k = idx & 511;
  Wt[idx] = f2bf(W[(k << 9) + n]);
}

__global__ void pack_zgr_k(const float* __restrict__ dgmW, unsigned short* __restrict__ Wt) {
  long idx = (long)blockIdx.x * 256 + threadIdx.x;  // 3*1536*1024
  int l = (int)(idx / (1536 * 1024));
  int rest = (int)(idx - (long)l * (1536 * 1024));
  int n = rest >> 10, k = rest & 1023;
  int g = n >> 9, nn = n & 511;
  const int xi0[3] = {0, 3, 6};
  const int xi1[3] = {2, 4, 8};
  const int si[3] = {1, 5, 7};
  float v;
  if (k < 512)
    v = dgmW[(((long)(l * 12 + xi0[g]) << 9) + k) * 512 + nn] +
        dgmW[(((long)(l * 12 + xi1[g]) << 9) + k) * 512 + nn];
  else
    v = dgmW[(((long)(l * 12 + si[g]) << 9) + (k - 512)) * 512 + nn];
  Wt[idx] = f2bf(v);
}

__global__ void pack_h_k(const float* __restrict__ dgmW, unsigned short* __restrict__ Wt) {
  long idx = (long)blockIdx.x * 256 + threadIdx.x;  // 3*512*1024
  int l = (int)(idx / (512 * 1024));
  int rest = (int)(idx - (long)l * (512 * 1024));
  int n = rest >> 10, k = rest & 1023;
  float v;
  if (k < 512)
    v = dgmW[(((long)(l * 12 + 9) << 9) + k) * 512 + n] +
        dgmW[(((long)(l * 12 + 11) << 9) + k) * 512 + n];
  else
    v = dgmW[(((long)(l * 12 + 10) << 9) + (k - 512)) * 512 + n];
  Wt[idx] = f2bf(v);
}

__global__ void pack_bias_k(const float* __restrict__ dgmb, float* __restrict__ bzgr,
                            float* __restrict__ bh) {
  int idx = blockIdx.x * 256 + threadIdx.x;  // 3*2048
  if (idx >= 3 * 2048) return;
  int l = idx >> 11, n = idx & 2047;
  const float* bl = dgmb + l * 12 * 512;
  if (n < 1536) {
    int g = n >> 9, nn = n & 511;
    bzgr[l * 1536 + n] =
        bl[(g * 3 + 0) * 512 + nn] + bl[(g * 3 + 1) * 512 + nn] + bl[(g * 3 + 2) * 512 + nn];
  } else {
    int nn = n - 1536;
    bh[l * 512 + nn] = bl[9 * 512 + nn] + bl[10 * 512 + nn] + bl[11 * 512 + nn];
  }
}

// ---------- front input layer ----------
__global__ void front0_k(const float* __restrict__ X, const float* __restrict__ t,
                         const float* __restrict__ Win, const float* __restrict__ bin,
                         unsigned short* __restrict__ x0, long row0) {
  long idx = (long)blockIdx.x * 256 + threadIdx.x;  // rows*512
  long r = idx >> 9;
  int c = (int)(idx & 511);
  long gr = row0 + r;
  float a = X[gr * 2] * Win[c] + X[gr * 2 + 1] * Win[512 + c] + t[gr] * Win[1024 + c] + bin[c];
  x0[idx] = f2bf(tanhf(a));
}

// ---------- output head ----------
__global__ void head_k(const unsigned short* __restrict__ S, const float* __restrict__ Wout,
                       const float* __restrict__ bout, float* __restrict__ out, long row0) {
  const int lane = threadIdx.x & 63, wid = threadIdx.x >> 6;
  const long r = (long)blockIdx.x * 4 + wid;
  bf16x8 sv = *(const bf16x8*)&S[r * 512 + lane * 8];
  float sum = 0.f;
#pragma unroll
  for (int i = 0; i < 8; ++i) sum += bf2f((unsigned short)sv[i]) * Wout[lane * 8 + i];
#pragma unroll
  for (int off = 32; off > 0; off >>= 1) sum += __shfl_down(sum, off);
  if (lane == 0) out[row0 + r] = sum + bout[0];
}

#define GLD(gsrc, ldst)                                                      \
  __builtin_amdgcn_global_load_lds(                                          \
      (const __attribute__((address_space(1))) void*)(gsrc),                 \
      (__attribute__((address_space(3))) void*)(ldst), 16, 0, 0)

// ---------- occupancy-first 128x64 GEMM ----------
// R9 post-mortem: every prior structure was capped at 2 waves/SIMD by
// acc-register pressure (R9: 120 VGPR + 128 AGPR = 248/wave) + LDS (128KB ->
// 1 block/CU); OccupancyPercent ~20% in ALL rounds, and R7's ablation
// signature (all marginals huge, no pipe saturated) = latency-coupling with
// nothing to hide it. Fix: small per-wave state. 4 waves (2Mx2N), wave out
// 64x32 = 8 frags = 32 AGPR, ~60 VGPR -> ~5 waves/SIMD; 24KB static LDS
// single-buffered -> 5-6 blocks/CU (~50-60% occupancy). Cross-block overlap
// (m114) hides the per-block stage/drain serialization.
// LDS: A [2 ks][128 rows][32 sh] = 16KB, B [2 ks][64 rows][32 sh] = 8KB.
// Swizzle (proven, 0 conflicts): granule ^= (row>>1)&3 on global source and
// ds_read; LDS dest linear.
template <int EPI, int KT>
__global__ __launch_bounds__(256, 4) void gemmS_k(
    const unsigned short* __restrict__ a0, const unsigned short* __restrict__ a1,
    const unsigned short* __restrict__ wt, const float* __restrict__ bias,
    unsigned short* __restrict__ o0, unsigned short* __restrict__ o1,
    unsigned short* __restrict__ o2, const unsigned short* __restrict__ e0,
    const unsigned short* __restrict__ e1) {
  constexpr int K = KT * 64;
  __shared__ unsigned short lds[12288];
  const int tid = threadIdx.x;
  const int lane = tid & 63, wid = tid >> 6;
  const int wm = wid >> 1, wn = wid & 1;
  const int lr = lane & 15, kk = lane >> 4;

  // bijective XCD swizzle (m204), col-fastest: the 24 (or 8) col-blocks of
  // one A-panel run consecutively on one XCD (A-panel + B stay L2-resident).
  const int gx = gridDim.x;
  const int nwg = gx * (int)gridDim.y;
  const int orig = (int)blockIdx.y * gx + (int)blockIdx.x;
  const int q = nwg >> 3, rr = nwg & 7;
  const int xcd = orig & 7, lo = orig >> 3;
  const int wg = ((xcd < rr) ? xcd * (q + 1) : rr * (q + 1) + (xcd - rr) * q) + lo;
  const long brow = (long)(wg / gx) * 128;
  const int bcol = (wg % gx) * 64;

  const int gp8 = ((kk ^ ((lr >> 1) & 3)) << 3);
  const int a_rd = (wm * 64 + lr) * 32 + gp8;         // + m*512 + ks*4096
  const int b_rd = 8192 + (wn * 32 + lr) * 32 + gp8;  // + n*512 + ks*2048

  f32x4 acc[4][2] = {};

  auto stage = [&](int kt) {
    const unsigned short* src = (KT == 16 && (kt & 8)) ? a1 : a0;
    const int ko = (kt & 7) * 64;
    // A: 1024 16B-units: u -> ks=u>>9, row=(u&511)>>2, granule=(u&3)
#pragma unroll
    for (int i = 0; i < 4; ++i) {
      const int u = tid + (i << 8);
      const int ks = u >> 9, rem = u & 511;
      const int row = rem >> 2;
      const int gl = (rem & 3) ^ ((row >> 1) & 3);
      GLD(src + (brow + row) * 512 + ko + ks * 32 + gl * 8, lds + u * 8);
    }
    // B: 512 16B-units: u -> ks=u>>8, row=(u&255)>>2
#pragma unroll
    for (int i = 0; i < 2; ++i) {
      const int u = tid + (i << 8);
      const int ks = u >> 8, rem = u & 255;
      const int row = rem >> 2;
      const int gl = (rem & 3) ^ ((row >> 1) & 3);
      GLD(wt + (size_t)(bcol + row) * K + kt * 64 + ks * 32 + gl * 8, lds + 8192 + u * 8);
    }
  };

  for (int t = 0; t < KT; ++t) {
    __syncthreads();  // prior tile's reads complete before overwrite
    stage(t);
    __syncthreads();  // compiler-inserted vmcnt(0): staged data visible
#pragma unroll
    for (int ks = 0; ks < 2; ++ks) {
      bf16x8 bf0 = *(const bf16x8*)(lds + b_rd + ks * 2048);
      bf16x8 bf1 = *(const bf16x8*)(lds + b_rd + ks * 2048 + 512);
      bf16x8 af[4];
#pragma unroll
      for (int m = 0; m < 4; ++m)
        af[m] = *(const bf16x8*)(lds + a_rd + ks * 4096 + m * 512);
      __builtin_amdgcn_s_setprio(1);
#pragma unroll
      for (int m = 0; m < 4; ++m) {
        acc[m][0] = __builtin_amdgcn_mfma_f32_16x16x32_bf16(af[m], bf0, acc[m][0], 0, 0, 0);
        acc[m][1] = __builtin_amdgcn_mfma_f32_16x16x32_bf16(af[m], bf1, acc[m][1], 0, 0, 0);
      }
      __builtin_amdgcn_s_setprio(0);
    }
  }

  // epilogue
#pragma unroll
  for (int m = 0; m < 4; ++m) {
#pragma unroll
    for (int n = 0; n < 2; ++n) {
      const int col = bcol + wn * 32 + n * 16 + lr;
      const float bs = bias[col];
#pragma unroll
      for (int j = 0; j < 4; ++j) {
        const long row = brow + wm * 64 + m * 16 + kk * 4 + j;
        float v = acc[m][n][j] + bs;
        if constexpr (EPI == 0) {
          o0[row * 512 + col] = f2bf(tanhf(v));
        } else if constexpr (EPI == 1) {
          unsigned short b = f2bf(v);
          o0[row * 512 + col] = b;
          o1[row * 512 + col] = b;
        } else if constexpr (EPI == 2) {
          const int g = col >> 9;
          const int nn = col & 511;
          const float sgv = sigm(v);
          if (g == 0) {
            o0[row * 512 + nn] = f2bf(sgv * bf2f(e0[row * 512 + nn]));  // Z*S
          } else if (g == 1) {
            o1[row * 512 + nn] = f2bf(1.0f - sgv);  // 1-G
          } else {
            o2[row * 512 + nn] = f2bf(sgv * bf2f(e0[row * 512 + nn]));  // S*R
          }
        } else {
          const float h = tanhf(v);
          const float omg = bf2f(e0[row * 512 + col]);
          const float zs = bf2f(e1[row * 512 + col]);
          o0[row * 512 + col] = f2bf(omg * h + zs);  // S_new
        }
      }
    }
  }
}

}  // namespace

extern "C" void kernel_launch(void* const* d_in, const int* in_sizes, int n_in,
                              void* d_out, int out_size, void* d_ws, size_t ws_size,
                              hipStream_t stream) {
  const float* X = (const float*)d_in[0];
  const float* t = (const float*)d_in[1];
  const float* W_in = (const float*)d_in[2];
  const float* b_in = (const float*)d_in[3];
  const float* W_h1 = (const float*)d_in[4];
  const float* b_h1 = (const float*)d_in[5];
  const float* W_hd = (const float*)d_in[6];
  const float* b_hd = (const float*)d_in[7];
  const float* dgm_W = (const float*)d_in[8];
  const float* dgm_b = (const float*)d_in[9];
  const float* W_out = (const float*)d_in[10];
  const float* b_out = (const float*)d_in[11];
  float* out = (float*)d_out;
  char* ws = (char*)d_ws;

  size_t off = 0;
  auto alloc = [&](size_t bytes) {
    size_t o = off;
    off = (off + bytes + 255) & ~(size_t)255;
    return o;
  };
  size_t o_wth1 = alloc((size_t)512 * 512 * 2);
  size_t o_wthd = alloc((size_t)512 * 512 * 2);
  size_t o_wtzgr = alloc((size_t)3 * 1536 * 1024 * 2);
  size_t o_wth = alloc((size_t)3 * 512 * 1024 * 2);
  size_t o_bzgr = alloc((size_t)3 * 1536 * 4);
  size_t o_bh = alloc((size_t)3 * 512 * 4);
  size_t actoff = off;

  unsigned short* wth1 = (unsigned short*)(ws + o_wth1);
  unsigned short* wthd = (unsigned short*)(ws + o_wthd);
  unsigned short* wtzgr = (unsigned short*)(ws + o_wtzgr);
  unsigned short* wth = (unsigned short*)(ws + o_wth);
  float* bzgr = (float*)(ws + o_bzgr);
  float* bh = (float*)(ws + o_bh);

  size_t avail = ws_size > actoff ? ws_size - actoff : 0;
  int nch = 1;
  while (nch < 256 && (size_t)(B_ROWS / nch) * 512 * 2 * 5 > avail) nch <<= 1;
  const int R = B_ROWS / nch;
  unsigned short* xb = (unsigned short*)(ws + actoff);
  unsigned short* Sb = xb + (size_t)R * 512;
  unsigned short* ZSb = Sb + (size_t)R * 512;
  unsigned short* OGb = ZSb + (size_t)R * 512;
  unsigned short* SRb = OGb + (size_t)R * 512;

  pack_t_k<<<1024, 256, 0, stream>>>(W_h1, wth1);
  pack_t_k<<<1024, 256, 0, stream>>>(W_hd, wthd);
  pack_zgr_k<<<18432, 256, 0, stream>>>(dgm_W, wtzgr);
  pack_h_k<<<6144, 256, 0, stream>>>(dgm_W, wth);
  pack_bias_k<<<24, 256, 0, stream>>>(dgm_b, bzgr, bh);

  const int MT = R / 128;
  for (int c = 0; c < nch; ++c) {
    long row0 = (long)c * R;
    dim3 g8(8, MT), g24(24, MT);
    // x0 = tanh(inp@W_in + b_in)  -> ZSb (scratch)
    front0_k<<<R * 2, 256, 0, stream>>>(X, t, W_in, b_in, ZSb, row0);
    // x1 = tanh(x0@W_h1 + b_h1)   -> OGb (scratch)
    gemmS_k<0, 8><<<g8, 256, 0, stream>>>(ZSb, ZSb, wth1, b_h1, OGb, nullptr, nullptr,
                                          nullptr, nullptr);
    // x = x1@W_hd + b_hd          -> xb and Sb
    gemmS_k<1, 8><<<g8, 256, 0, stream>>>(OGb, OGb, wthd, b_hd, xb, Sb, nullptr,
                                          nullptr, nullptr);
    for (int l = 0; l < 3; ++l) {
      // gates: [x|S] @ Wzgr -> Z*S, 1-G, S*R
      gemmS_k<2, 16><<<g24, 256, 0, stream>>>(xb, Sb, wtzgr + (size_t)l * 1536 * 1024,
                                              bzgr + l * 1536, ZSb, OGb, SRb, Sb, nullptr);
      // H + S update: [x|S*R] @ Wh ; S = (1-G)*tanh + Z*S
      gemmS_k<3, 16><<<g8, 256, 0, stream>>>(xb, SRb, wth + (size_t)l * 512 * 1024,
                                             bh + l * 512, Sb, nullptr, nullptr, OGb, ZSb);
    }
    head_k<<<R / 4, 256, 0, stream>>>(Sb, W_out, b_out, out, row0);
  }
}